// Round 10
// baseline (563.834 us; speedup 1.0000x reference)
//
#include <hip/hip_runtime.h>
#include <hip/hip_bf16.h>
#include <stdint.h>

typedef short bf16x8 __attribute__((ext_vector_type(8)));
typedef float f32x4 __attribute__((ext_vector_type(4)));
typedef unsigned short u16x8 __attribute__((ext_vector_type(8)));

#define GLB(p)  ((__attribute__((address_space(1))) void*)(uintptr_t)(p))
#define LDSP(p) ((__attribute__((address_space(3))) void*)(p))

// Split fp32 into bf16 hi + bf16 lo (both RNE). x ≈ hi + lo with ~2^-17 rel residual.
__device__ __forceinline__ void bf16_split(float x, unsigned short& h, unsigned short& l) {
  unsigned u = __float_as_uint(x);
  unsigned hb = (u + 0x7FFFu + ((u >> 16) & 1u)) >> 16;
  h = (unsigned short)hb;
  float d = x - __uint_as_float(hb << 16);
  unsigned u2 = __float_as_uint(d);
  l = (unsigned short)((u2 + 0x7FFFu + ((u2 >> 16) & 1u)) >> 16);
}

// Prepass 1: elementwise split of x -> A_hi, A_lo ([M][K] bf16, k-contiguous)
__global__ void convert_split_k(const float* __restrict__ in,
                                unsigned short* __restrict__ hi,
                                unsigned short* __restrict__ lo, long n) {
  long i = ((long)blockIdx.x * blockDim.x + threadIdx.x) * 8;
  if (i + 8 > n) return;
  float v[8];
  *(float4*)(&v[0]) = *(const float4*)(in + i);
  *(float4*)(&v[4]) = *(const float4*)(in + i + 4);
  u16x8 vh, vl;
#pragma unroll
  for (int e = 0; e < 8; ++e) {
    unsigned short h, l;
    bf16_split(v[e], h, l);
    vh[e] = h; vl[e] = l;
  }
  *(u16x8*)(hi + i) = vh;
  *(u16x8*)(lo + i) = vl;
}

// Prepass 2 (LDS-tiled): W[Dk][U] fp32 -> Bt_hi, Bt_lo [U][Dk] bf16.
__global__ __launch_bounds__(256) void transpose_split_k(
    const float* __restrict__ in, unsigned short* __restrict__ hiT,
    unsigned short* __restrict__ loT, int Dk, int U) {
  __shared__ unsigned short lh[16][264];
  __shared__ unsigned short ll[16][264];
  const int t = threadIdx.x;
  const int ublocks = U >> 4;
  const int u0 = (blockIdx.x % ublocks) << 4;
  const int d0 = (blockIdx.x / ublocks) << 8;
  const int ul = t & 15, dl0 = t >> 4;
#pragma unroll
  for (int p = 0; p < 16; ++p) {
    const int d = dl0 + p * 16;
    float x = in[(long)(d0 + d) * U + (u0 + ul)];
    unsigned short h, l;
    bf16_split(x, h, l);
    lh[ul][d] = h;
    ll[ul][d] = l;
  }
  __syncthreads();
  const int ur = t >> 5, ck = t & 31;
#pragma unroll
  for (int p = 0; p < 2; ++p) {
    const int u = ur + p * 8;
    u16x8 vh = *(const u16x8*)&lh[u][ck * 8];
    u16x8 vl = *(const u16x8*)&ll[u][ck * 8];
    *(u16x8*)(hiT + (long)(u0 + u) * Dk + d0 + ck * 8) = vh;
    *(u16x8*)(loT + (long)(u0 + u) * Dk + d0 + ck * 8) = vl;
  }
}

// ---------------------------------------------------------------------------
// Ring-pipelined bf16x3 GEMM, counted vmcnt (T4). 256x256 tile, 8 waves
// (2M x 4N), wave = 128x64 output, 16x16x32 MFMA, BK=32.
// Virtual K' = 3K: chunk t in [0,nK)->Ahi*Bhi, [nK,2nK)->Alo*Bhi,
// [2nK,3nK)->Ahi*Blo  (the 3 bf16x3 terms as one long GEMM; arrays unchanged).
// LDS = ring of 4 chunk-slots x {A,B} x [256][32] bf16 = 128 KB. Staging runs
// 3 chunks ahead; per iter ONE barrier + vmcnt(8): 8 younger loads stay in
// flight across the barrier (never drain to 0 mid-loop). Tail peeled with
// vmcnt(4)/vmcnt(0).
// vmcnt ledger (audited r10): steady iter t holds 12 outstanding
// (chunks t,t+1,t+2) -> vmcnt(8) retires exactly chunk t; stage(t+3)
// restores 12. Prologue t=0 identical; tail 12->8->4 matches 8/4/0 literals.
// RAW: own-wave vmcnt retires chunk-t loads, barrier publishes all waves'.
// WAR: stage(t+3) overwrites slot (t-1)&3, whose last reads completed before
// each wave passed the iter-t barrier (reads precede MFMA precede barrier).
// Swizzle (verified r3-r7): store slot s of row r holds kgroup s^((r>>1)&3);
// read slot kg^((l15>>1)&3); frag row bases are 16-aligned -> masks match.
// No explicit lgkm drain: plain LDS loads let the compiler emit fine-grained
// lgkmcnt between ds_read and MFMA (m97 behavior).
// ---------------------------------------------------------------------------
#define STAGE_CHUNK(U_) do { \
  const int u_ = (U_); \
  const int seg_ = (u_ >= 2 * nK) ? 2 : (u_ >= nK) ? 1 : 0; \
  const unsigned short* gA_ = (seg_ == 1) ? pAl : pAh; \
  const unsigned short* gB_ = (seg_ == 2) ? pBl : pBh; \
  const long kb_ = (long)(u_ - seg_ * nK) << 5; \
  unsigned short* lb_ = &ring[u_ & 3][0][0]; \
  __builtin_amdgcn_global_load_lds(GLB(gA_ + c0 + kb_), LDSP(lb_ + (wid << 9)), 16, 0, 0); \
  __builtin_amdgcn_global_load_lds(GLB(gA_ + c1 + kb_), LDSP(lb_ + 4096 + (wid << 9)), 16, 0, 0); \
  __builtin_amdgcn_global_load_lds(GLB(gB_ + c0 + kb_), LDSP(lb_ + 8192 + (wid << 9)), 16, 0, 0); \
  __builtin_amdgcn_global_load_lds(GLB(gB_ + c1 + kb_), LDSP(lb_ + 12288 + (wid << 9)), 16, 0, 0); \
} while (0)

#define RING_ITER(T_, VMASM_, DOSTAGE_) do { \
  const int sl_ = (T_) & 3; \
  asm volatile(VMASM_ ::: "memory"); \
  __builtin_amdgcn_s_barrier(); \
  __builtin_amdgcn_sched_barrier(0); \
  if (DOSTAGE_) STAGE_CHUNK((T_) + 3); \
  const unsigned short* sa_ = &ring[sl_][0][0]; \
  const unsigned short* sb_ = &ring[sl_][1][0]; \
  bf16x8 aF[8], bF[4]; \
  _Pragma("unroll") for (int f_ = 0; f_ < 8; ++f_) \
    aF[f_] = *(const bf16x8*)&sa_[wm * 4096 + f_ * 512 + foff]; \
  _Pragma("unroll") for (int f_ = 0; f_ < 4; ++f_) \
    bF[f_] = *(const bf16x8*)&sb_[wn * 2048 + f_ * 512 + foff]; \
  __builtin_amdgcn_s_setprio(1); \
  _Pragma("unroll") for (int i_ = 0; i_ < 8; ++i_) \
  _Pragma("unroll") for (int j_ = 0; j_ < 4; ++j_) \
    acc[i_][j_] = __builtin_amdgcn_mfma_f32_16x16x32_bf16(aF[i_], bF[j_], acc[i_][j_], 0, 0, 0); \
  __builtin_amdgcn_s_setprio(0); \
} while (0)

__global__ __launch_bounds__(512, 2) void gemm_bf16x3_ring(
    const unsigned short* __restrict__ Ahi, const unsigned short* __restrict__ Alo,
    const unsigned short* __restrict__ Bhi, const unsigned short* __restrict__ Blo,
    const float* __restrict__ nmean, const float* __restrict__ nstd,
    const float* __restrict__ eps, float* __restrict__ out,
    int M, int N, int K)
{
  __shared__ __align__(16) unsigned short ring[4][2][256 * 32];

  const int tid  = threadIdx.x;
  const int wid  = tid >> 6;
  const int lane = tid & 63;
  const int l15  = lane & 15;
  const int kg   = lane >> 4;
  const int wm   = wid >> 2;   // 0..1
  const int wn   = wid & 3;    // 0..3

  const int nbm = M >> 8, nbn = N >> 8, nwg = nbm * nbn;
  const int bid = blockIdx.x;
  const int swz = ((nwg & 7) == 0) ? ((bid & 7) * (nwg >> 3) + (bid >> 3)) : bid;
  const int bm = swz % nbm, bn = swz / nbm;
  const long rowA0 = (long)bm << 8;
  const long rowB0 = (long)bn << 8;

  const unsigned short* pAh = Ahi + rowA0 * K;
  const unsigned short* pAl = Alo + rowA0 * K;
  const unsigned short* pBh = Bhi + rowB0 * K;
  const unsigned short* pBl = Blo + rowB0 * K;

  // staging lane geometry: thread covers 16B chunks e0=tid (rows 0-127) and
  // e1=tid+512 (rows 128-255); source k pre-swizzled (involution w/ read side)
  const int e0 = tid, e1 = tid + 512;
  const int r0 = e0 >> 2, r1 = e1 >> 2;
  const long c0 = (long)r0 * K + (long)(((e0 & 3) ^ ((r0 >> 1) & 3)) << 3);
  const long c1 = (long)r1 * K + (long)(((e1 & 3) ^ ((r1 >> 1) & 3)) << 3);

  // per-lane fragment read offset (elements, within a [16][32] frag row-block)
  const int foff = l15 * 32 + ((kg ^ ((l15 >> 1) & 3)) << 3);

  f32x4 acc[8][4];
#pragma unroll
  for (int i = 0; i < 8; ++i)
#pragma unroll
    for (int j = 0; j < 4; ++j) acc[i][j] = (f32x4)0.0f;

  const int nK = K >> 5;      // chunks per segment
  const int nt = 3 * nK;      // total virtual chunks (3 bf16x3 terms)

  // prologue: stage chunks 0,1,2 (12 loads in flight)
  STAGE_CHUNK(0);
  STAGE_CHUNK(1);
  STAGE_CHUNK(2);

  for (int t = 0; t < nt - 2; ++t)
    RING_ITER(t, "s_waitcnt vmcnt(8)", (t + 3) < nt);
  RING_ITER(nt - 2, "s_waitcnt vmcnt(4)", false);
  RING_ITER(nt - 1, "s_waitcnt vmcnt(0)", false);

  // epilogue: C/D layout col=lane&15, row=4*(lane>>4)+r; fused noise
  const float NS = 2.44140625e-4f; // 2^-12
  const long r0o = rowA0 + wm * 128;
  const long c0o = rowB0 + wn * 64;
#pragma unroll
  for (int i = 0; i < 8; ++i)
#pragma unroll
    for (int j = 0; j < 4; ++j) {
      const long col = c0o + j * 16 + l15;
      const float mn = nmean[col];
      const float sd = nstd[col];
#pragma unroll
      for (int r = 0; r < 4; ++r) {
        const long row = r0o + i * 16 + kg * 4 + r;
        const long o = row * N + col;
        out[o] = acc[i][j][r] + (mn + sd * eps[o]) * NS;
      }
    }
}

// Insurance: plain fp32 LDS-tiled GEMM (only for odd shapes / tiny workspace).
__global__ __launch_bounds__(1024) void fb_gemm(
    const float* __restrict__ A, const float* __restrict__ B,
    const float* __restrict__ nmean, const float* __restrict__ nstd,
    const float* __restrict__ eps, float* __restrict__ out,
    int M, int N, int K) {
  __shared__ float sA[32][33];
  __shared__ float sB[32][33];
  const int tx = threadIdx.x & 31, ty = threadIdx.x >> 5;
  const int row = blockIdx.y * 32 + ty;
  const int col = blockIdx.x * 32 + tx;
  float acc = 0.f;
  for (int kt = 0; kt < K; kt += 32) {
    sA[ty][tx] = A[(long)row * K + kt + tx];
    sB[ty][tx] = B[(long)(kt + ty) * N + col];
    __syncthreads();
#pragma unroll
    for (int k = 0; k < 32; ++k) acc += sA[ty][k] * sB[k][tx];
    __syncthreads();
  }
  const long o = (long)row * N + col;
  out[o] = acc + (nmean[col] + nstd[col] * eps[o]) * 2.44140625e-4f;
}

extern "C" void kernel_launch(void* const* d_in, const int* in_sizes, int n_in,
                              void* d_out, int out_size, void* d_ws, size_t ws_size,
                              hipStream_t stream) {
  (void)n_in; (void)out_size;
  const float* x     = (const float*)d_in[0];
  const float* w     = (const float*)d_in[1];
  const float* nmean = (const float*)d_in[2];
  const float* nstd  = (const float*)d_in[3];
  const float* eps   = (const float*)d_in[4];
  float* out = (float*)d_out;

  const int U  = in_sizes[2];
  const int Dk = in_sizes[1] / U;
  const int Bm = in_sizes[0] / Dk;

  const size_t elemsA = (size_t)Bm * Dk;
  const size_t elemsB = (size_t)Dk * U;
  const size_t need = 2 * (elemsA + elemsB) * sizeof(unsigned short);

  const bool ok = (ws_size >= need) &&
                  (Bm % 256 == 0) && (U % 256 == 0) && (Dk % 256 == 0) &&
                  ((elemsA % 8) == 0);

  if (ok) {
    unsigned short* Ahi  = (unsigned short*)d_ws;
    unsigned short* Alo  = Ahi + elemsA;
    unsigned short* BhiT = Alo + elemsA;
    unsigned short* BloT = BhiT + elemsB;
    const long nA = (long)elemsA;
    const int gridA = (int)((nA / 8 + 255) / 256);
    convert_split_k<<<gridA, 256, 0, stream>>>(x, Ahi, Alo, nA);
    transpose_split_k<<<(U >> 4) * (Dk >> 8), 256, 0, stream>>>(w, BhiT, BloT, Dk, U);
    const int nwg = (Bm >> 8) * (U >> 8);
    gemm_bf16x3_ring<<<nwg, 512, 0, stream>>>(Ahi, Alo, BhiT, BloT,
                                              nmean, nstd, eps, out, Bm, U, Dk);
  } else {
    dim3 g(U / 32, Bm / 32);
    fb_gemm<<<g, 1024, 0, stream>>>(x, w, nmean, nstd, eps, out, Bm, U, Dk);
  }
}